// Round 6
// baseline (16.605 us; speedup 1.0000x reference)
//
#include <hip/hip_runtime.h>

#define NPTS 512
#define DIM  128
#define MARGIN 0.5f
#define CNT_EPS 1e-8f
#define NBLK 256            // 2 anchors per block

__device__ __forceinline__ float dot4(float4 a, float4 b) {
    return a.x * b.x + a.y * b.y + a.z * b.z + a.w * b.w;
}

// ---------------------------------------------------------------------------
// One block (1024 thr = 16 waves) per 2 anchors; grid 256 = 1 block/CU,
// 4 waves/SIMD at VGPR<=128. Waves 0-7 -> anchor 2*bid, waves 8-15 ->
// anchor 2*bid+1. Both halves stream the SAME xj rows on the same CU, so
// unique L2 traffic per CU halves vs 1-anchor blocks.
// Distance phase per half: 4 lanes per row j, 16 rows per wave, 4 passes.
// Then per half: one thread per row k -> single-step compaction + pair loop.
// Tail: per-wave shuffle reduce, 16-partial combine, plain global store.
// ---------------------------------------------------------------------------
__global__ __launch_bounds__(1024, 4)
void triplet_row_kernel(const float* __restrict__ x,
                        const int* __restrict__ labels,
                        float* __restrict__ psum,
                        int* __restrict__ pcnt) {
    __shared__ float drow[2][NPTS];   // distance rows for the 2 anchors
    __shared__ float posv[2][NPTS];
    __shared__ int   lab[NPTS];
    __shared__ int   npos_sh[2];
    __shared__ float wsum[16];
    __shared__ int   wcnt[16];

    const int tid = threadIdx.x;     // 0..1023
    const int h   = tid >> 9;        // half: 0 or 1
    const int t   = tid & 511;       // index within half
    const int w8  = t >> 6;          // wave-in-half 0..7
    const int l   = tid & 63;        // lane
    const int g   = l >> 2;          // row-group 0..15 within wave
    const int c   = l & 3;           // column slot 0..3

    const int i  = 2 * blockIdx.x + h;   // this half's anchor

    if (tid < NPTS) lab[tid] = labels[tid];
    if (tid < 2)    npos_sh[tid] = 0;
    const int li = labels[i];

    // anchor row fragment in registers: columns c+4*it (it=0..7)
    const float4* xi4 = (const float4*)(x + i * DIM);
    float4 xf[8];
#pragma unroll
    for (int it = 0; it < 8; ++it) xf[it] = xi4[c + 4 * it];

    // sqi = ||xi||^2 : per-lane partial, 4-lane butterfly
    float sqi = 0.f;
#pragma unroll
    for (int it = 0; it < 8; ++it) sqi += dot4(xf[it], xf[it]);
    sqi += __shfl_xor(sqi, 1, 64);
    sqi += __shfl_xor(sqi, 2, 64);

    // distance rows: pass p covers rows p*128 + w8*16 + g (per half)
#pragma unroll 2
    for (int pass = 0; pass < 4; ++pass) {
        const int j = pass * 128 + w8 * 16 + g;
        const float4* xj4 = (const float4*)(x + j * DIM);
        float dp = 0.f, sp = 0.f;
#pragma unroll
        for (int it = 0; it < 8; ++it) {
            float4 b = xj4[c + 4 * it];
            dp += dot4(b, xf[it]);
            sp += dot4(b, b);
        }
        dp += __shfl_xor(dp, 1, 64);
        dp += __shfl_xor(dp, 2, 64);
        sp += __shfl_xor(sp, 1, 64);
        sp += __shfl_xor(sp, 2, 64);
        if (c == 0) {
            float dsq = sqi + sp - 2.f * dp;
            dsq = dsq > 0.f ? dsq : 0.f;
            // reference's zero-mask only affects exact-zero entries (the
            // diagonal), excluded by validity -> plain sqrt exact here.
            drow[h][j] = (dsq == 0.f) ? 0.f : sqrtf(dsq);
        }
    }
    __syncthreads();

    // compact positives: one thread per row per half (~8 atomics/half)
    if (lab[t] == li && t != i) {
        int p = atomicAdd(&npos_sh[h], 1);
        posv[h][p] = drow[h][t] + MARGIN;
    }
    __syncthreads();
    const int npos = npos_sh[h];

    // pair loop: this thread owns k = t within its half
    const bool  isneg = (lab[t] != li);
    const float dk    = drow[h][t];
    float lsum = 0.f;
    int   lcnt = 0;
    for (int p = 0; p < npos; ++p) {
        float v = posv[h][p] - dk;       // d_ij - d_ik + margin
        if (isneg && v > 0.f) {
            lsum += v;
            lcnt += (v > CNT_EPS) ? 1 : 0;
        }
    }

    // per-wave shuffle reduce, then 16-partial combine (both anchors summed)
#pragma unroll
    for (int off = 1; off < 64; off <<= 1) {
        lsum += __shfl_xor(lsum, off, 64);
        lcnt += __shfl_xor(lcnt, off, 64);
    }
    const int wid = tid >> 6;            // 0..15
    if (l == 0) { wsum[wid] = lsum; wcnt[wid] = lcnt; }
    __syncthreads();
    if (tid == 0) {
        float s = 0.f;
        int   cc = 0;
#pragma unroll
        for (int q = 0; q < 16; ++q) { s += wsum[q]; cc += wcnt[q]; }
        psum[blockIdx.x] = s;            // plain stores; kernel-boundary
        pcnt[blockIdx.x] = cc;           // coherence is runtime-managed
    }
}

// ---------------------------------------------------------------------------
// Finalize: ONE wave, one float4/int4 per lane, shuffle reduce, no LDS.
// ---------------------------------------------------------------------------
__global__ void finalize_kernel(const float4* __restrict__ psum4,
                                const int4* __restrict__ pcnt4,
                                float* __restrict__ out) {
    const int t = threadIdx.x;           // 0..63 ; 64*4 = 256 partials
    float4 a  = psum4[t];
    int4   ca = pcnt4[t];
    float s  = a.x + a.y + a.z + a.w;
    int   cc = ca.x + ca.y + ca.z + ca.w;
#pragma unroll
    for (int off = 1; off < 64; off <<= 1) {
        s  += __shfl_xor(s, off, 64);
        cc += __shfl_xor(cc, off, 64);
    }
    if (t == 0) out[0] = s / (float)cc;
}

extern "C" void kernel_launch(void* const* d_in, const int* in_sizes, int n_in,
                              void* d_out, int out_size, void* d_ws, size_t ws_size,
                              hipStream_t stream) {
    const float* x      = (const float*)d_in[0];   // [512,128] fp32
    const int*   labels = (const int*)d_in[1];     // [512] int32
    float*       out    = (float*)d_out;           // scalar fp32

    float* psum = (float*)d_ws;          // 256 floats (fully overwritten)
    int*   pcnt = (int*)(psum + NBLK);   // 256 ints  (fully overwritten)

    triplet_row_kernel<<<NBLK, 1024, 0, stream>>>(x, labels, psum, pcnt);
    finalize_kernel<<<1, 64, 0, stream>>>((const float4*)psum,
                                          (const int4*)pcnt, out);
}